// Round 7
// baseline (208.597 us; speedup 1.0000x reference)
//
#include <hip/hip_runtime.h>

// GAT: B=256, N=64, K=12, D=128
// Algebra: wq_eff = Wq @ wa_q, wk_eff = Wk @ wa_k; V-projection commutes
// with the attention average: out = h_bar @ Wv + bv * (sum attn).
//
// R6: restructure — one pair per 32-lane HALF-WAVE (R3/R4/R5 post-mortem:
// the allocator pinned VGPR=64 three times, erasing every multi-buffer
// pipeline; fighting regalloc lost. New shape makes low-register == fast):
//  - lane li owns features 4li..4li+3 of ALL 13 vectors of its half's pair:
//    14 independent float4 loads per lane, one burst, fillBuffer-style MLP.
//  - both halves share every shuffle instruction (2 pairs per DS op);
//    serial DS depth per wave drops ~4x (7 layers vs ~32).
//  - 16-value reduce-scatter (4 stages + xor16 finish, all within-half);
//    after e-broadcasts each lane holds all 13 e's -> S computed locally,
//    no combine stage, no divergent epilogue.
//  - amdgpu_waves_per_eu(4,4): allocator budget fixed at 128 VGPR, no
//    incentive to crush to the 64-reg/8-wave tier.
//  - ROWS=8, grid 2048; Phase B: 8x128 tile, 1 row/thread, b128 quad reads.

#define B_  256
#define N_  64
#define K_  12
#define D_  128
#define BN  (B_ * N_)          // 16384 (b,n) pairs
#define ROWS 8                 // pairs per block; one per half-wave
#define HB_STRIDE 132          // 528B rows: 16B-aligned

#define PIN4(v)  asm volatile("" : "+v"(v.x), "+v"(v.y), "+v"(v.z), "+v"(v.w))

// ws float layout: [0..127] wq_eff | [128..255] wk_eff | [256] cq | [257] ckb
// ---------------------------------------------------------------------------
__global__ void prep_kernel(const float* __restrict__ Wq, const float* __restrict__ bq,
                            const float* __restrict__ Wk, const float* __restrict__ bk,
                            const float* __restrict__ wa_q, const float* __restrict__ wa_k,
                            float* __restrict__ ws) {
    int g = blockIdx.x;
    int l = threadIdx.x;
    const float* row;
    const float* wa;
    float* outp;
    if (g < 128)      { row = Wq + g * D_;         wa = wa_q; outp = ws + g; }
    else if (g < 256) { row = Wk + (g - 128) * D_; wa = wa_k; outp = ws + 128 + (g - 128); }
    else if (g == 256){ row = bq;                  wa = wa_q; outp = ws + 256; }
    else              { row = bk;                  wa = wa_k; outp = ws + 257; }

    float2 r = ((const float2*)row)[l];
    float2 w = ((const float2*)wa)[l];
    float p = r.x * w.x + r.y * w.y;
    #pragma unroll
    for (int m = 1; m < 64; m <<= 1) p += __shfl_xor(p, m, 64);
    if (l == 0) *outp = p;
}

// ---------------------------------------------------------------------------
// grid = BN/8 = 2048 blocks x 256 threads. Block owns 8 pairs; each 32-lane
// half-wave owns one pair. Lane li holds features 4li..4li+3 of all 13
// vectors. Value index g=li&15: g=0..11 neighbor-k dots, 12 node-k, 13
// node-q, 14/15 pad. RS leaves lane li with value (li&15) fully reduced.
__global__ void __launch_bounds__(256)
__attribute__((amdgpu_waves_per_eu(4, 4)))
fused_kernel(const float* __restrict__ nodes, const float* __restrict__ neigh,
             const float* __restrict__ mask, const float* __restrict__ ba_p,
             const float* __restrict__ ws, const float* __restrict__ Wv,
             const float* __restrict__ bv, float* __restrict__ out) {
    __shared__ float hb[ROWS * HB_STRIDE];
    __shared__ float scL[ROWS];

    const int t    = threadIdx.x;
    const int wave = t >> 6;
    const int l    = t & 63;
    const int li   = l & 31;       // lane within half: features 4li..4li+3
    const int hf   = l >> 5;       // which half -> which pair
    const int g    = li & 15;      // value index (duplicated across li>=16)
    const int hsel = l & 32;       // shuffle source base for my half

    const float cq  = ws[256];
    const float ckb = ws[257];
    const float ba  = ba_p[0];
    const float cst = cq + ckb + ba;
    const float4 wqe4 = ((const float4*)ws)[li];          // wq_eff[4li..]
    const float4 wke4 = ((const float4*)(ws + 128))[li];  // wk_eff[4li..]

    const int idx = blockIdx.x * ROWS + wave * 2 + hf;    // this half's pair

    // ---- one burst: 12 neighbor float4 + node float4 + mask (independent) ----
    const float4* gp = (const float4*)(neigh + (size_t)idx * (K_ * D_));
    float4 xv[K_];
    #pragma unroll
    for (int j = 0; j < K_; ++j) xv[j] = gp[j * 32 + li];
    const float4 nv = ((const float4*)(nodes + (size_t)idx * D_))[li];
    // mval doubles as the node-slot '1' so e_own = exp * mval everywhere
    const float mval = (g < K_) ? mask[(size_t)idx * K_ + g]
                                : ((g == 12) ? 1.0f : 0.0f);

    // ---- per-lane partial dots: 16 values (2 pad) ----
    float v[16];
    #pragma unroll
    for (int j = 0; j < K_; ++j)
        v[j] = xv[j].x*wke4.x + xv[j].y*wke4.y + xv[j].z*wke4.z + xv[j].w*wke4.w;
    v[12] = nv.x*wke4.x + nv.y*wke4.y + nv.z*wke4.z + nv.w*wke4.w;
    v[13] = nv.x*wqe4.x + nv.y*wqe4.y + nv.z*wqe4.z + nv.w*wqe4.w;
    v[14] = 0.0f;
    v[15] = 0.0f;

    // keep xv/nv live in registers for the pooling (no re-load)
    PIN4(xv[0]); PIN4(xv[1]); PIN4(xv[2]);  PIN4(xv[3]);
    PIN4(xv[4]); PIN4(xv[5]); PIN4(xv[6]);  PIN4(xv[7]);
    PIN4(xv[8]); PIN4(xv[9]); PIN4(xv[10]); PIN4(xv[11]);

    // ---- reduce-scatter: 4 stages (bits 1,2,4,8) + xor16 finish ----
    float r8[8];
    {
        const bool hi = (l & 1);
        #pragma unroll
        for (int m = 0; m < 8; ++m) {
            float take = hi ? v[2*m] : v[2*m + 1];
            float keep = hi ? v[2*m + 1] : v[2*m];
            r8[m] = keep + __shfl_xor(take, 1, 64);
        }
    }
    float r4[4];
    {
        const bool hi = (l & 2);
        #pragma unroll
        for (int m = 0; m < 4; ++m) {
            float take = hi ? r8[2*m] : r8[2*m + 1];
            float keep = hi ? r8[2*m + 1] : r8[2*m];
            r4[m] = keep + __shfl_xor(take, 2, 64);
        }
    }
    float r2[2];
    {
        const bool hi = (l & 4);
        #pragma unroll
        for (int m = 0; m < 2; ++m) {
            float take = hi ? r4[2*m] : r4[2*m + 1];
            float keep = hi ? r4[2*m + 1] : r4[2*m];
            r2[m] = keep + __shfl_xor(take, 4, 64);
        }
    }
    float c;
    {
        const bool hi = (l & 8);
        float take = hi ? r2[0] : r2[1];
        float keep = hi ? r2[1] : r2[0];
        c = keep + __shfl_xor(take, 8, 64);
    }
    c += __shfl_xor(c, 16, 64);        // within-half: full 128-feature dot
    // lane li now holds the full dot of value (li&15)

    // ---- scores: every lane computes e for ITS value ----
    const float pq  = __shfl(c, hsel | 13, 64);   // node q-dot (my half)
    const float pkn = __shfl(c, hsel | 12, 64);   // node k-dot (unused pad-safe)
    (void)pkn;
    const float base = pq + cst;
    float s_own = base + c;
    s_own = (s_own >= 0.0f) ? s_own : 0.2f * s_own;   // LeakyReLU(0.2)
    const float e_own = __expf(s_own) * mval;          // mval: mask / 1 / 0

    // ---- broadcasts: each lane gathers all 13 e's; pooling + S local ----
    float S;
    float4 acc;
    {
        const float en = __shfl(e_own, hsel | 12, 64);     // node slot
        acc.x = en * nv.x;
        acc.y = en * nv.y;
        acc.z = en * nv.z;
        acc.w = en * nv.w;
        S = en;
    }
    #pragma unroll
    for (int j = 0; j < K_; ++j) {
        const float ej = __shfl(e_own, hsel | j, 64);      // neighbor j
        acc.x += ej * xv[j].x;
        acc.y += ej * xv[j].y;
        acc.z += ej * xv[j].z;
        acc.w += ej * xv[j].w;
        S += ej;
    }
    const float inv = 1.0f / (S + 1e-16f);

    const int lrow = wave * 2 + hf;                        // 0..7
    float4 o;
    o.x = acc.x * inv;
    o.y = acc.y * inv;
    o.z = acc.z * inv;
    o.w = acc.w * inv;
    *(float4*)(hb + lrow * HB_STRIDE + 4 * li) = o;        // all 32 lanes
    if (li == 0) scL[lrow] = S * inv;                      // sum of attn
    __syncthreads();

    // ---- Phase B: out[8x128] = hb @ Wv + bv * scale ----
    // thread (rg=t>>5, cg=t&31): row rg, cols 4cg..4cg+3. hb read as b128
    // row-quads: 2 distinct addrs per wave instr (broadcast, free).
    const int rg = t >> 5;                 // 0..7
    const int cg = t & 31;
    const float4* wv4 = (const float4*)Wv; // [k][32] of float4
    const float* hrow = hb + rg * HB_STRIDE;

    float4 vacc = make_float4(0.0f, 0.0f, 0.0f, 0.0f);
    #pragma unroll 8
    for (int kq = 0; kq < 32; ++kq) {
        const float4 a = *(const float4*)(hrow + 4 * kq);
        #pragma unroll
        for (int e = 0; e < 4; ++e) {
            const float4 w = wv4[(4 * kq + e) * 32 + cg];
            const float f = (e == 0) ? a.x : (e == 1) ? a.y : (e == 2) ? a.z : a.w;
            vacc.x += f * w.x;
            vacc.y += f * w.y;
            vacc.z += f * w.z;
            vacc.w += f * w.w;
        }
    }

    const float4 bvv = ((const float4*)bv)[cg];
    const float  s   = scL[rg];
    float4 o2;
    o2.x = vacc.x + bvv.x * s;
    o2.y = vacc.y + bvv.y * s;
    o2.z = vacc.z + bvv.z * s;
    o2.w = vacc.w + bvv.w * s;
    *(float4*)(out + (size_t)(blockIdx.x * ROWS + rg) * D_ + cg * 4) = o2;
}

// ---------------------------------------------------------------------------
extern "C" void kernel_launch(void* const* d_in, const int* in_sizes, int n_in,
                              void* d_out, int out_size, void* d_ws, size_t ws_size,
                              hipStream_t stream) {
    const float* nodes = (const float*)d_in[0];
    const float* neigh = (const float*)d_in[1];
    const float* mask  = (const float*)d_in[2];
    const float* Wq    = (const float*)d_in[3];
    const float* bq    = (const float*)d_in[4];
    const float* Wk    = (const float*)d_in[5];
    const float* bk    = (const float*)d_in[6];
    const float* Wv    = (const float*)d_in[7];
    const float* bv    = (const float*)d_in[8];
    const float* wa_q  = (const float*)d_in[9];
    const float* wa_k  = (const float*)d_in[10];
    const float* ba    = (const float*)d_in[11];
    float* out = (float*)d_out;
    float* ws  = (float*)d_ws;

    prep_kernel<<<258, 64, 0, stream>>>(Wq, bq, Wk, bk, wa_q, wa_k, ws);
    fused_kernel<<<BN / ROWS, 256, 0, stream>>>(nodes, neigh, mask, ba, ws, Wv, bv, out);
}

// Round 9
// 191.613 us; speedup vs baseline: 1.0886x; 1.0886x over previous
//
#include <hip/hip_runtime.h>

// GAT: B=256, N=64, K=12, D=128
// Algebra: wq_eff = Wq @ wa_q, wk_eff = Wk @ wa_k; V-projection commutes
// with the attention average: out = h_bar @ Wv + bv * (sum attn).
//
// R7 (resubmit; previous round hit GPU-acquisition timeout, never ran;
// cleaned a dead duplicate shuffle in RS stage 1):
// global_load_lds double-buffered tile pipeline (decisive experiment:
// R1-R6 all land 55-76us regardless of structure at ~1.9 TB/s delivery;
// either exposed-latency-burstiness (H1) or a platform delivery ceiling
// (H2)). Block = 16 pairs = 4 tiles x 4 pairs:
//  - stage tile t+1 (26KB, fully contiguous: consecutive pairs) into LDS
//    buf[(t+1)&1] via 7 block-wide global_load_lds instrs — async, no VGPR
//    roundtrip, issued BEFORE compute(t).
//  - compute tile t entirely from LDS (ds_read_b128 + R4's verified
//    shuffle math); compute path has ZERO global-memory dependency.
//  - __syncthreads() per tile = the m97 2-phase pattern.
//  - VGPR ~56 naturally -> no regalloc fight. LDS ~61KB -> 2 blocks/CU.
// Decision rule: <=45us => H1, keep pushing; 55-62us => H2, ROOFLINE.

#define B_  256
#define N_  64
#define K_  12
#define D_  128
#define BN  (B_ * N_)          // 16384 (b,n) pairs
#define TP    4                // pairs per tile
#define TILES 4                // tiles per block
#define ROWS  16               // pairs per block = TP*TILES
#define HB_STRIDE 132          // 528B rows: 16B-aligned

// ws float layout: [0..127] wq_eff | [128..255] wk_eff | [256] cq | [257] ckb
// ---------------------------------------------------------------------------
__global__ void prep_kernel(const float* __restrict__ Wq, const float* __restrict__ bq,
                            const float* __restrict__ Wk, const float* __restrict__ bk,
                            const float* __restrict__ wa_q, const float* __restrict__ wa_k,
                            float* __restrict__ ws) {
    int g = blockIdx.x;
    int l = threadIdx.x;
    const float* row;
    const float* wa;
    float* outp;
    if (g < 128)      { row = Wq + g * D_;         wa = wa_q; outp = ws + g; }
    else if (g < 256) { row = Wk + (g - 128) * D_; wa = wa_k; outp = ws + 128 + (g - 128); }
    else if (g == 256){ row = bq;                  wa = wa_q; outp = ws + 256; }
    else              { row = bk;                  wa = wa_k; outp = ws + 257; }

    float2 r = ((const float2*)row)[l];
    float2 w = ((const float2*)wa)[l];
    float p = r.x * w.x + r.y * w.y;
    #pragma unroll
    for (int m = 1; m < 64; m <<= 1) p += __shfl_xor(p, m, 64);
    if (l == 0) *outp = p;
}

// direct HBM->LDS, 16B per lane
__device__ __forceinline__ void gll16(const float* g, float* l) {
    __builtin_amdgcn_global_load_lds(
        (const __attribute__((address_space(1))) unsigned int*)g,
        (__attribute__((address_space(3))) unsigned int*)l, 16, 0, 0);
}

// ---------------------------------------------------------------------------
// grid = BN/16 = 1024 blocks x 256 threads. Block owns 16 pairs; per tile
// each wave owns one pair (64 lanes). Lane l: half h=l>>5 covers neighbor
// slots {2i+h}; li=l&31 owns features 4li..4li+3. 8-value reduce-scatter
// (3 stages + xor8 + xor16, all within-half) -> lane (l&7) holds one dot.
__global__ void __launch_bounds__(256)
fused_kernel(const float* __restrict__ nodes, const float* __restrict__ neigh,
             const float* __restrict__ mask, const float* __restrict__ ba_p,
             const float* __restrict__ ws, const float* __restrict__ Wv,
             const float* __restrict__ bv, float* __restrict__ out) {
    __shared__ float nb[2][TP * K_ * D_];   // 2 x 24KB neighbor tiles
    __shared__ float ndb[2][TP * D_];       // 2 x 2KB node tiles
    __shared__ float mb[2][TP * K_];        // 2 x 192B mask tiles
    __shared__ float hb[ROWS * HB_STRIDE];  // 8.4KB pooled rows
    __shared__ float scL[ROWS];

    const int t    = threadIdx.x;
    const int wave = t >> 6;
    const int l    = t & 63;
    const int li   = l & 31;
    const int h    = l >> 5;
    const int j8   = l & 7;

    const float cq  = ws[256];
    const float ckb = ws[257];
    const float ba  = ba_p[0];
    const float cst = cq + ckb + ba;
    const float4 wqe4 = ((const float4*)ws)[li];          // wq_eff[4li..]
    const float4 wke4 = ((const float4*)(ws + 128))[li];  // wk_eff[4li..]

    const int base_pair = blockIdx.x * ROWS;

    // ---- async stage of one 4-pair tile (26KB, contiguous streams) ----
    #define STAGE(buf, tt) do {                                               \
        const int tb_ = base_pair + (tt) * TP;                                \
        const float* ns_ = neigh + (size_t)tb_ * (K_ * D_);                   \
        _Pragma("unroll")                                                     \
        for (int i_ = 0; i_ < 6; ++i_)                                        \
            gll16(ns_ + i_ * 1024 + t * 4, &nb[buf][i_ * 1024 + t * 4]);      \
        if (wave < 2)                                                         \
            gll16(nodes + (size_t)tb_ * D_ + t * 4, &ndb[buf][t * 4]);        \
        else if (wave == 2 && l < 12)                                         \
            gll16(mask + (size_t)tb_ * K_ + l * 4, &mb[buf][l * 4]);          \
    } while (0)

    // ---- attention for pair (wave) of tile tt from LDS buf ----
    #define COMPUTE(buf, tt) do {                                             \
        const float* nbp_ = &nb[buf][wave * (K_ * D_)];                       \
        const float* ndp_ = &ndb[buf][wave * D_];                             \
        const float4 nv_ = *(const float4*)(ndp_ + 4 * li);                   \
        float4 x0_ = *(const float4*)(nbp_ + (0 + h) * D_ + 4 * li);          \
        float4 x1_ = *(const float4*)(nbp_ + (2 + h) * D_ + 4 * li);          \
        float4 x2_ = *(const float4*)(nbp_ + (4 + h) * D_ + 4 * li);          \
        float4 x3_ = *(const float4*)(nbp_ + (6 + h) * D_ + 4 * li);          \
        float4 x4_ = *(const float4*)(nbp_ + (8 + h) * D_ + 4 * li);          \
        float4 x5_ = *(const float4*)(nbp_ + (10 + h) * D_ + 4 * li);         \
        float v0 = x0_.x*wke4.x + x0_.y*wke4.y + x0_.z*wke4.z + x0_.w*wke4.w; \
        float v1 = x1_.x*wke4.x + x1_.y*wke4.y + x1_.z*wke4.z + x1_.w*wke4.w; \
        float v2 = x2_.x*wke4.x + x2_.y*wke4.y + x2_.z*wke4.z + x2_.w*wke4.w; \
        float v3 = x3_.x*wke4.x + x3_.y*wke4.y + x3_.z*wke4.z + x3_.w*wke4.w; \
        float v4 = x4_.x*wke4.x + x4_.y*wke4.y + x4_.z*wke4.z + x4_.w*wke4.w; \
        float v5 = x5_.x*wke4.x + x5_.y*wke4.y + x5_.z*wke4.z + x5_.w*wke4.w; \
        float v6 = nv_.x*wke4.x + nv_.y*wke4.y + nv_.z*wke4.z + nv_.w*wke4.w; \
        float v7 = nv_.x*wqe4.x + nv_.y*wqe4.y + nv_.z*wqe4.z + nv_.w*wqe4.w; \
        float A0, A1, A2, A3;                                                 \
        {                                                                     \
            const bool hi_ = (l & 1);                                         \
            float g0 = __shfl_xor(hi_ ? v0 : v1, 1, 64);                      \
            float g1 = __shfl_xor(hi_ ? v2 : v3, 1, 64);                      \
            float g2 = __shfl_xor(hi_ ? v4 : v5, 1, 64);                      \
            float g3 = __shfl_xor(hi_ ? v6 : v7, 1, 64);                      \
            A0 = (hi_ ? v1 : v0) + g0;                                        \
            A1 = (hi_ ? v3 : v2) + g1;                                        \
            A2 = (hi_ ? v5 : v4) + g2;                                        \
            A3 = (hi_ ? v7 : v6) + g3;                                        \
        }                                                                     \
        float B0, B1;                                                         \
        {                                                                     \
            const bool hi_ = (l & 2);                                         \
            float g0 = __shfl_xor(hi_ ? A0 : A1, 2, 64);                      \
            float g1 = __shfl_xor(hi_ ? A2 : A3, 2, 64);                      \
            B0 = (hi_ ? A1 : A0) + g0;                                        \
            B1 = (hi_ ? A3 : A2) + g1;                                        \
        }                                                                     \
        float c;                                                              \
        {                                                                     \
            const bool hi_ = (l & 4);                                         \
            float g = __shfl_xor(hi_ ? B0 : B1, 4, 64);                       \
            c = (hi_ ? B1 : B0) + g;                                          \
        }                                                                     \
        c += __shfl_xor(c, 8, 64);                                            \
        c += __shfl_xor(c, 16, 64);                                           \
        const float pq_  = __shfl(c, 7, 8);                                   \
        const float pkn_ = __shfl(c, 6, 8);                                   \
        const float base_ = pq_ + cst;                                        \
        float s0_ = base_ + pkn_;                                             \
        s0_ = (s0_ >= 0.0f) ? s0_ : 0.2f * s0_;                               \
        const float e0_ = __expf(s0_);                                        \
        float sj_ = base_ + c;                                                \
        sj_ = (sj_ >= 0.0f) ? sj_ : 0.2f * sj_;                               \
        float ej_ = 0.0f;                                                     \
        if (j8 < 6) ej_ = __expf(sj_) * mb[buf][wave * K_ + 2 * j8 + h];      \
        const float an_ = (h == 0) ? e0_ : 0.0f;                              \
        float ax = an_ * nv_.x, ay = an_ * nv_.y;                             \
        float az = an_ * nv_.z, aw = an_ * nv_.w;                             \
        float Se_ = 0.0f;                                                     \
        {                                                                     \
            float bi_;                                                        \
            bi_ = __shfl(ej_, 0, 8); Se_ += bi_;                              \
            ax += bi_*x0_.x; ay += bi_*x0_.y; az += bi_*x0_.z; aw += bi_*x0_.w; \
            bi_ = __shfl(ej_, 1, 8); Se_ += bi_;                              \
            ax += bi_*x1_.x; ay += bi_*x1_.y; az += bi_*x1_.z; aw += bi_*x1_.w; \
            bi_ = __shfl(ej_, 2, 8); Se_ += bi_;                              \
            ax += bi_*x2_.x; ay += bi_*x2_.y; az += bi_*x2_.z; aw += bi_*x2_.w; \
            bi_ = __shfl(ej_, 3, 8); Se_ += bi_;                              \
            ax += bi_*x3_.x; ay += bi_*x3_.y; az += bi_*x3_.z; aw += bi_*x3_.w; \
            bi_ = __shfl(ej_, 4, 8); Se_ += bi_;                              \
            ax += bi_*x4_.x; ay += bi_*x4_.y; az += bi_*x4_.z; aw += bi_*x4_.w; \
            bi_ = __shfl(ej_, 5, 8); Se_ += bi_;                              \
            ax += bi_*x5_.x; ay += bi_*x5_.y; az += bi_*x5_.z; aw += bi_*x5_.w; \
        }                                                                     \
        ax += __shfl_xor(ax, 32, 64);                                         \
        ay += __shfl_xor(ay, 32, 64);                                         \
        az += __shfl_xor(az, 32, 64);                                         \
        aw += __shfl_xor(aw, 32, 64);                                         \
        Se_ += __shfl_xor(Se_, 32, 64);                                       \
        const float S_   = e0_ + Se_;                                         \
        const float inv_ = 1.0f / (S_ + 1e-16f);                              \
        if (h == 0) {                                                         \
            const int lrow_ = (tt) * TP + wave;                               \
            float4 o_;                                                        \
            o_.x = ax * inv_;                                                 \
            o_.y = ay * inv_;                                                 \
            o_.z = az * inv_;                                                 \
            o_.w = aw * inv_;                                                 \
            *(float4*)(hb + lrow_ * HB_STRIDE + 4 * li) = o_;                 \
            if (li == 0) scL[lrow_] = S_ * inv_;                              \
        }                                                                     \
    } while (0)

    // ---- pipeline: stage(t+1) overlaps compute(t) ----
    STAGE(0, 0);
    __syncthreads();
    #pragma unroll
    for (int tt = 0; tt < TILES; ++tt) {
        const int cur = tt & 1;
        if (tt + 1 < TILES) STAGE((tt + 1) & 1, tt + 1);
        __builtin_amdgcn_sched_barrier(0);      // keep stage issued early
        COMPUTE(cur, tt);
        __syncthreads();                        // drains vmcnt for next tile
    }
    #undef STAGE
    #undef COMPUTE

    // ---- Phase B: out[16x128] = hb @ Wv + bv * scale ----
    // thread (rg=t>>5, cg=t&31) does rows {rg, rg+8}, cols 4cg..4cg+3.
    const int rg = t >> 5;
    const int cg = t & 31;
    const float4* wv4 = (const float4*)Wv;        // [k][32] of float4
    const float* hr0 = hb + rg * HB_STRIDE;
    const float* hr1 = hb + (rg + 8) * HB_STRIDE;

    float4 acc0 = make_float4(0.0f, 0.0f, 0.0f, 0.0f);
    float4 acc1 = make_float4(0.0f, 0.0f, 0.0f, 0.0f);
    #pragma unroll 8
    for (int kq = 0; kq < 32; ++kq) {
        const float4 a0 = *(const float4*)(hr0 + 4 * kq);
        const float4 a1 = *(const float4*)(hr1 + 4 * kq);
        #pragma unroll
        for (int e = 0; e < 4; ++e) {
            const float4 w = wv4[(4 * kq + e) * 32 + cg];
            const float f0 = (e == 0) ? a0.x : (e == 1) ? a0.y : (e == 2) ? a0.z : a0.w;
            const float f1 = (e == 0) ? a1.x : (e == 1) ? a1.y : (e == 2) ? a1.z : a1.w;
            acc0.x += f0 * w.x; acc0.y += f0 * w.y;
            acc0.z += f0 * w.z; acc0.w += f0 * w.w;
            acc1.x += f1 * w.x; acc1.y += f1 * w.y;
            acc1.z += f1 * w.z; acc1.w += f1 * w.w;
        }
    }

    const float4 bvv = ((const float4*)bv)[cg];
    {
        const float s = scL[rg];
        float4 o;
        o.x = acc0.x + bvv.x * s;
        o.y = acc0.y + bvv.y * s;
        o.z = acc0.z + bvv.z * s;
        o.w = acc0.w + bvv.w * s;
        *(float4*)(out + (size_t)(base_pair + rg) * D_ + cg * 4) = o;
    }
    {
        const float s = scL[rg + 8];
        float4 o;
        o.x = acc1.x + bvv.x * s;
        o.y = acc1.y + bvv.y * s;
        o.z = acc1.z + bvv.z * s;
        o.w = acc1.w + bvv.w * s;
        *(float4*)(out + (size_t)(base_pair + rg + 8) * D_ + cg * 4) = o;
    }
}

// ---------------------------------------------------------------------------
extern "C" void kernel_launch(void* const* d_in, const int* in_sizes, int n_in,
                              void* d_out, int out_size, void* d_ws, size_t ws_size,
                              hipStream_t stream) {
    const float* nodes = (const float*)d_in[0];
    const float* neigh = (const float*)d_in[1];
    const float* mask  = (const float*)d_in[2];
    const float* Wq    = (const float*)d_in[3];
    const float* bq    = (const float*)d_in[4];
    const float* Wk    = (const float*)d_in[5];
    const float* bk    = (const float*)d_in[6];
    const float* Wv    = (const float*)d_in[7];
    const float* bv    = (const float*)d_in[8];
    const float* wa_q  = (const float*)d_in[9];
    const float* wa_k  = (const float*)d_in[10];
    const float* ba    = (const float*)d_in[11];
    float* out = (float*)d_out;
    float* ws  = (float*)d_ws;

    prep_kernel<<<258, 64, 0, stream>>>(Wq, bq, Wk, bk, wa_q, wa_k, ws);
    fused_kernel<<<BN / ROWS, 256, 0, stream>>>(nodes, neigh, mask, ba, ws, Wv, bv, out);
}